// Round 8
// baseline (3161.348 us; speedup 1.0000x reference)
//
#include <hip/hip_runtime.h>
#include <hip/hip_cooperative_groups.h>

namespace cg = cooperative_groups;

typedef __bf16 bf16x8 __attribute__((ext_vector_type(8)));
typedef float f32x4 __attribute__((ext_vector_type(4)));
typedef short short8 __attribute__((ext_vector_type(8)));

__device__ __forceinline__ unsigned short f2bf_u(float f) {
    unsigned u = __builtin_bit_cast(unsigned, f);
    u += 0x7FFFu + ((u >> 16) & 1u);   // RNE
    return (unsigned short)(u >> 16);
}
__device__ __forceinline__ float bf2f(unsigned short h) {
    unsigned u = ((unsigned)h) << 16;
    return __builtin_bit_cast(float, u);
}

#define GLOAD_LDS16(gsrc, ldst)                                                        \
    __builtin_amdgcn_global_load_lds((const __attribute__((address_space(1))) void*)(gsrc), \
                                     (__attribute__((address_space(3))) void*)(ldst), 16, 0, 0)

// ==================================================================
// Shared device bodies (verified round 6)
// ==================================================================
__device__ __forceinline__
void prop_node(const unsigned short* __restrict__ hin, const unsigned short* __restrict__ zbf,
               const int* __restrict__ rowptr, const int* __restrict__ csr_src,
               const float* __restrict__ csr_w, const float* __restrict__ dinv,
               void* __restrict__ hout, bool outf32, int node, int lane) {
    float di = dinv[node];
    int base = node << 6;
    float acc = bf2f(hin[base + lane]) * (di * di);
    int e = rowptr[node], e1 = rowptr[node + 1];
    for (; e + 8 <= e1; e += 8) {
        int sx[8]; float ww[8]; unsigned short v[8];
        #pragma unroll
        for (int j = 0; j < 8; ++j) { sx[j] = csr_src[e + j]; ww[j] = csr_w[e + j]; }
        #pragma unroll
        for (int j = 0; j < 8; ++j) v[j] = hin[(sx[j] << 6) + lane];
        #pragma unroll
        for (int j = 0; j < 8; ++j) acc = fmaf(bf2f(v[j]), ww[j], acc);
    }
    for (; e < e1; ++e)
        acc = fmaf(bf2f(hin[(csr_src[e] << 6) + lane]), csr_w[e], acc);
    float res = 0.9f * acc + 0.1f * bf2f(zbf[base + lane]);
    if (outf32) ((float*)hout)[base + lane] = res;
    else        ((unsigned short*)hout)[base + lane] = f2bf_u(res);
}

// Double-buffered MFMA GEMM tile: BM=128, BN=64, BK=64, 512 thr (8 waves 4x2),
// global_load_lds w=16, XOR-swizzle kg^(row&7), prefetch-ahead, 1 barrier/K-step.
template<int KDIM, int LDC, bool RELU>
__device__ __forceinline__
void gemm_tile(const short* __restrict__ A, const short* __restrict__ Bh,
               const short* __restrict__ Bl, const float* __restrict__ bias,
               short* __restrict__ C, int M, int m0, int n0,
               short* sAp, short* sBp) {
    constexpr int NT = KDIM / 64;
    const int tid  = threadIdx.x;
    const int lane = tid & 63;
    const int wave = tid >> 6;
    const int wr = wave >> 1, wc = wave & 1;
    const int lr = lane & 15;
    const int lk = lane >> 4;
    const int l8r = lane >> 3;
    const int l8u = lane & 7;

    f32x4 acc[2][2];
    #pragma unroll
    for (int mi = 0; mi < 2; ++mi)
        #pragma unroll
        for (int ni = 0; ni < 2; ++ni) acc[mi][ni] = {0.f, 0.f, 0.f, 0.f};

    auto stage = [&](int buf, int k0) {
        #pragma unroll
        for (int p = 0; p < 2; ++p) {
            int row = p * 64 + wave * 8 + l8r;
            int grow = m0 + row; if (grow > M - 1) grow = M - 1;
            const short* s = A + (size_t)grow * KDIM + k0 + ((l8u ^ (row & 7)) << 3);
            GLOAD_LDS16(s, sAp + buf * 8192 + p * 4096 + wave * 512);
        }
        int row = wave * 8 + l8r;
        size_t goff = (size_t)(n0 + row) * KDIM + k0 + ((l8u ^ (row & 7)) << 3);
        GLOAD_LDS16(Bh + goff, sBp + (buf * 2 + 0) * 4096 + wave * 512);
        GLOAD_LDS16(Bl + goff, sBp + (buf * 2 + 1) * 4096 + wave * 512);
    };

    stage(0, 0);
    asm volatile("s_waitcnt vmcnt(0)" ::: "memory");
    __builtin_amdgcn_s_barrier();
    asm volatile("" ::: "memory");

    int cur = 0;
    #pragma unroll 1
    for (int t = 0; t < NT; ++t) {
        if (t + 1 < NT) stage(cur ^ 1, (t + 1) * 64);
        #pragma unroll
        for (int ks = 0; ks < 2; ++ks) {
            int kg = ks * 4 + lk;
            bf16x8 af[2], bhf[2], blf[2];
            #pragma unroll
            for (int mi = 0; mi < 2; ++mi) {
                int row = wr * 32 + mi * 16 + lr;
                af[mi] = *reinterpret_cast<const bf16x8*>(
                    &sAp[cur * 8192 + row * 64 + ((kg ^ (row & 7)) << 3)]);
            }
            #pragma unroll
            for (int ni = 0; ni < 2; ++ni) {
                int row = wc * 32 + ni * 16 + lr;
                int idx = row * 64 + ((kg ^ (row & 7)) << 3);
                bhf[ni] = *reinterpret_cast<const bf16x8*>(&sBp[(cur * 2 + 0) * 4096 + idx]);
                blf[ni] = *reinterpret_cast<const bf16x8*>(&sBp[(cur * 2 + 1) * 4096 + idx]);
            }
            #pragma unroll
            for (int mi = 0; mi < 2; ++mi)
                #pragma unroll
                for (int ni = 0; ni < 2; ++ni) {
                    acc[mi][ni] = __builtin_amdgcn_mfma_f32_16x16x32_bf16(af[mi], bhf[ni], acc[mi][ni], 0, 0, 0);
                    acc[mi][ni] = __builtin_amdgcn_mfma_f32_16x16x32_bf16(af[mi], blf[ni], acc[mi][ni], 0, 0, 0);
                }
        }
        asm volatile("s_waitcnt vmcnt(0)" ::: "memory");
        __builtin_amdgcn_s_barrier();
        asm volatile("" ::: "memory");
        cur ^= 1;
    }

    #pragma unroll
    for (int ni = 0; ni < 2; ++ni) {
        int col = n0 + wc * 32 + ni * 16 + lr;
        float bv = bias[col];
        #pragma unroll
        for (int mi = 0; mi < 2; ++mi) {
            #pragma unroll
            for (int r = 0; r < 4; ++r) {
                int row = m0 + wr * 32 + mi * 16 + lk * 4 + r;
                if (row < M) {
                    float v = acc[mi][ni][r] + bv;
                    if (RELU) v = fmaxf(v, 0.0f);
                    C[(size_t)row * LDC + col] = (short)f2bf_u(v);
                }
            }
        }
    }
}

// ==================================================================
// Cooperative kernels (all fully grid-stride -> any grid size correct)
// ==================================================================
__global__ __launch_bounds__(256, 4)
void pre_kernel(const float* __restrict__ x, const void* __restrict__ ei,
                const float* __restrict__ W1, const float* __restrict__ W2,
                short* __restrict__ xbf, short* __restrict__ W1h, short* __restrict__ W1l,
                short* __restrict__ W2h, short* __restrict__ W2l,
                int* __restrict__ flag, int* __restrict__ src, int* __restrict__ dst,
                int* __restrict__ counts, float* __restrict__ dinv,
                int* __restrict__ rowptr, int* __restrict__ cursor,
                int* __restrict__ bs, int* __restrict__ bsoff,
                int* __restrict__ csr_src, float* __restrict__ csr_w,
                int N, int E) {
    cg::grid_group grid = cg::this_grid();
    __shared__ int sdata[256];
    __shared__ int sflag;
    const int tid = threadIdx.x;
    const int gtid = blockIdx.x * 256 + tid;
    const int gsize = gridDim.x * 256;

    for (int i = gtid; i < N; i += gsize) counts[i] = 0;
    if (blockIdx.x == 0) {
        if (tid == 0) sflag = 0;
        __syncthreads();
        unsigned v = 0;
        for (int i = tid * 2 + 1; i < 2048; i += 512) v |= ((const unsigned*)ei)[i];
        if (v) atomicOr(&sflag, 1);
        __syncthreads();
        if (tid == 0) *flag = sflag;
    }
    const int n1 = 256 * 512, n2 = 64 * 256;
    for (int i = gtid; i < n1; i += gsize) {
        float w0 = W1[i];
        unsigned short h = f2bf_u(w0);
        W1h[i] = (short)h;
        W1l[i] = (short)f2bf_u(w0 - bf2f(h));
    }
    for (int i = gtid; i < n2; i += gsize) {
        float w0 = W2[i];
        unsigned short h = f2bf_u(w0);
        W2h[i] = (short)h;
        W2l[i] = (short)f2bf_u(w0 - bf2f(h));
    }
    const int n8 = N * 64;
    for (int i = gtid; i < n8; i += gsize) {
        const float4* p = reinterpret_cast<const float4*>(x + (size_t)i * 8);
        float4 v0 = p[0], v1 = p[1];
        short8 sh;
        sh[0] = (short)f2bf_u(v0.x); sh[1] = (short)f2bf_u(v0.y);
        sh[2] = (short)f2bf_u(v0.z); sh[3] = (short)f2bf_u(v0.w);
        sh[4] = (short)f2bf_u(v1.x); sh[5] = (short)f2bf_u(v1.y);
        sh[6] = (short)f2bf_u(v1.z); sh[7] = (short)f2bf_u(v1.w);
        *reinterpret_cast<short8*>(xbf + (size_t)i * 8) = sh;
    }
    grid.sync();

    {
        const int fl = *flag;
        for (int e = gtid; e < E; e += gsize) {
            int s, d;
            if (fl) { const int* p = (const int*)ei; s = p[e]; d = p[E + e]; }
            else    { const long long* p = (const long long*)ei; s = (int)p[e]; d = (int)p[E + e]; }
            src[e] = s; dst[e] = d;
            atomicAdd(&counts[d], 1);
        }
    }
    grid.sync();

    for (int i = gtid; i < N; i += gsize) dinv[i] = rsqrtf((float)counts[i] + 1.0f);
    const int nchunks = (N + 255) >> 8;
    for (int c = blockIdx.x; c < nchunks; c += gridDim.x) {
        int i = (c << 8) + tid;
        int v = (i < N) ? counts[i] : 0;
        sdata[tid] = v;
        __syncthreads();
        #pragma unroll
        for (int off = 1; off < 256; off <<= 1) {
            int t = (tid >= off) ? sdata[tid - off] : 0;
            __syncthreads();
            sdata[tid] += t;
            __syncthreads();
        }
        if (i < N) rowptr[i] = sdata[tid] - v;
        if (tid == 255) bs[c] = sdata[255];
        __syncthreads();
    }
    grid.sync();

    if (blockIdx.x == 0) {
        int v = (tid < nchunks) ? bs[tid] : 0;
        sdata[tid] = v;
        __syncthreads();
        #pragma unroll
        for (int off = 1; off < 256; off <<= 1) {
            int t = (tid >= off) ? sdata[tid - off] : 0;
            __syncthreads();
            sdata[tid] += t;
            __syncthreads();
        }
        if (tid < nchunks) bsoff[tid] = sdata[tid] - v;
    }
    grid.sync();

    for (int i = gtid; i < N; i += gsize) {
        int r = rowptr[i] + bsoff[i >> 8];
        rowptr[i] = r;
        cursor[i] = r;
    }
    if (gtid == 0) rowptr[N] = E;
    grid.sync();

    for (int e = gtid; e < E; e += gsize) {
        int s = src[e], d = dst[e];
        int pos = atomicAdd(&cursor[d], 1);
        csr_src[pos] = s;
        csr_w[pos] = dinv[s] * dinv[d];
    }
}

__global__ __launch_bounds__(512, 4)
void gemm_fused(const short* __restrict__ xbf, const short* __restrict__ W1h,
                const short* __restrict__ W1l, const float* __restrict__ b1,
                short* __restrict__ Hbf, const short* __restrict__ W2h,
                const short* __restrict__ W2l, const float* __restrict__ b2,
                short* __restrict__ zbf, int M) {
    __shared__ short sAp[2 * 128 * 64];
    __shared__ short sBp[2 * 2 * 64 * 64];
    cg::grid_group grid = cg::this_grid();
    const int mgrid = (M + 127) >> 7;
    const int nt1 = mgrid * 4;
    for (int t = blockIdx.x; t < nt1; t += gridDim.x)
        gemm_tile<512, 256, true>(xbf, W1h, W1l, b1, Hbf, M, (t >> 2) * 128, (t & 3) * 64, sAp, sBp);
    grid.sync();
    for (int t = blockIdx.x; t < mgrid; t += gridDim.x)
        gemm_tile<256, 64, false>(Hbf, W2h, W2l, b2, zbf, M, t * 128, 0, sAp, sBp);
}

__global__ __launch_bounds__(256, 8)
void prop_fused(const unsigned short* __restrict__ zbf, unsigned short* __restrict__ hA,
                unsigned short* __restrict__ hB, const int* __restrict__ rowptr,
                const int* __restrict__ csr_src, const float* __restrict__ csr_w,
                const float* __restrict__ dinv, float* __restrict__ dout,
                int n, int ksteps) {
    cg::grid_group grid = cg::this_grid();
    const int lane = threadIdx.x & 63;
    const int gwave0 = blockIdx.x * 4 + (threadIdx.x >> 6);
    const int nwaves = gridDim.x * 4;
    for (int s = 0; s < ksteps; ++s) {
        if (s) grid.sync();
        const unsigned short* hin = (s == 0) ? zbf : ((s & 1) ? hA : hB);
        void* hout = (s == ksteps - 1) ? (void*)dout : ((s & 1) ? (void*)hB : (void*)hA);
        const bool last = (s == ksteps - 1);
        for (int node = gwave0; node < n; node += nwaves)
            prop_node(hin, zbf, rowptr, csr_src, csr_w, dinv, hout, last, node, lane);
    }
}

// ==================================================================
// Classic fallback kernels (round-6 proven chain)
// ==================================================================
__global__ void detect_kernel(const unsigned int* __restrict__ edges, int* flag) {
    unsigned v = 0;
    for (int i = threadIdx.x * 2 + 1; i < 2048; i += 512) v |= edges[i];
    if (v) atomicOr(flag, 1);
}

__global__ void convert_count_kernel(const void* __restrict__ edges, const int* __restrict__ flag,
                                     int* __restrict__ src, int* __restrict__ dst,
                                     int* __restrict__ counts, int E) {
    int e = blockIdx.x * 256 + threadIdx.x;
    if (e >= E) return;
    int s, d;
    if (*flag) { const int* p = (const int*)edges; s = p[e]; d = p[E + e]; }
    else       { const long long* p = (const long long*)edges; s = (int)p[e]; d = (int)p[E + e]; }
    src[e] = s;
    dst[e] = d;
    atomicAdd(&counts[d], 1);
}

__global__ void dinv_kernel(const int* __restrict__ counts, float* __restrict__ dinv, int n) {
    int i = blockIdx.x * 256 + threadIdx.x;
    if (i < n) dinv[i] = rsqrtf((float)counts[i] + 1.0f);
}

__global__ void blocksum_kernel(const int* __restrict__ counts, int* __restrict__ bs, int n) {
    __shared__ int sdata[256];
    int i = blockIdx.x * 256 + threadIdx.x;
    sdata[threadIdx.x] = (i < n) ? counts[i] : 0;
    __syncthreads();
    #pragma unroll
    for (int off = 128; off > 0; off >>= 1) {
        if (threadIdx.x < off) sdata[threadIdx.x] += sdata[threadIdx.x + off];
        __syncthreads();
    }
    if (threadIdx.x == 0) bs[blockIdx.x] = sdata[0];
}

__global__ void scanbs_kernel(const int* __restrict__ bs, int* __restrict__ bsoff, int nb) {
    __shared__ int sdata[256];
    int tid = threadIdx.x;
    int v = (tid < nb) ? bs[tid] : 0;
    sdata[tid] = v;
    __syncthreads();
    #pragma unroll
    for (int off = 1; off < 256; off <<= 1) {
        int t = (tid >= off) ? sdata[tid - off] : 0;
        __syncthreads();
        sdata[tid] += t;
        __syncthreads();
    }
    if (tid < nb) bsoff[tid] = sdata[tid] - v;
}

__global__ void scanblock_kernel(const int* __restrict__ counts, const int* __restrict__ bsoff,
                                 int* __restrict__ rowptr, int* __restrict__ cursor, int n) {
    __shared__ int sdata[256];
    int tid = threadIdx.x;
    int i = blockIdx.x * 256 + tid;
    int v = (i < n) ? counts[i] : 0;
    sdata[tid] = v;
    __syncthreads();
    #pragma unroll
    for (int off = 1; off < 256; off <<= 1) {
        int t = (tid >= off) ? sdata[tid - off] : 0;
        __syncthreads();
        sdata[tid] += t;
        __syncthreads();
    }
    int excl = bsoff[blockIdx.x] + sdata[tid] - v;
    if (i < n) { rowptr[i] = excl; cursor[i] = excl; }
    if (i == n - 1) rowptr[n] = excl + v;
}

__global__ void fill_kernel(const int* __restrict__ src, const int* __restrict__ dst,
                            const float* __restrict__ dinv, int* __restrict__ cursor,
                            int* __restrict__ csr_src, float* __restrict__ csr_w, int E) {
    int e = blockIdx.x * 256 + threadIdx.x;
    if (e >= E) return;
    int s = src[e], d = dst[e];
    int pos = atomicAdd(&cursor[d], 1);
    csr_src[pos] = s;
    csr_w[pos] = dinv[s] * dinv[d];
}

__global__ void wsplit_kernel(const float* __restrict__ W, short* __restrict__ Wh,
                              short* __restrict__ Wl, int n) {
    int i = blockIdx.x * 256 + threadIdx.x;
    if (i >= n) return;
    float w = W[i];
    unsigned short h = f2bf_u(w);
    Wh[i] = (short)h;
    Wl[i] = (short)f2bf_u(w - bf2f(h));
}

__global__ __launch_bounds__(256)
void cvtbf_kernel(const float* __restrict__ x, short* __restrict__ out, int n8) {
    for (int i = blockIdx.x * 256 + threadIdx.x; i < n8; i += gridDim.x * 256) {
        const float4* p = reinterpret_cast<const float4*>(x + (size_t)i * 8);
        float4 v0 = p[0], v1 = p[1];
        short8 s;
        s[0] = (short)f2bf_u(v0.x); s[1] = (short)f2bf_u(v0.y);
        s[2] = (short)f2bf_u(v0.z); s[3] = (short)f2bf_u(v0.w);
        s[4] = (short)f2bf_u(v1.x); s[5] = (short)f2bf_u(v1.y);
        s[6] = (short)f2bf_u(v1.z); s[7] = (short)f2bf_u(v1.w);
        *reinterpret_cast<short8*>(out + (size_t)i * 8) = s;
    }
}

__global__ __launch_bounds__(512)
void gemm1_k(const short* __restrict__ xbf, const short* __restrict__ W1h,
             const short* __restrict__ W1l, const float* __restrict__ b1,
             short* __restrict__ Hbf, int M) {
    __shared__ short sAp[2 * 128 * 64];
    __shared__ short sBp[2 * 2 * 64 * 64];
    int t = blockIdx.x;
    gemm_tile<512, 256, true>(xbf, W1h, W1l, b1, Hbf, M, (t >> 2) * 128, (t & 3) * 64, sAp, sBp);
}

__global__ __launch_bounds__(512)
void gemm2_k(const short* __restrict__ Hbf, const short* __restrict__ W2h,
             const short* __restrict__ W2l, const float* __restrict__ b2,
             short* __restrict__ zbf, int M) {
    __shared__ short sAp[2 * 128 * 64];
    __shared__ short sBp[2 * 2 * 64 * 64];
    gemm_tile<256, 64, false>(Hbf, W2h, W2l, b2, zbf, M, blockIdx.x * 128, 0, sAp, sBp);
}

__global__ __launch_bounds__(256)
void prop_step(const unsigned short* __restrict__ hin, const unsigned short* __restrict__ zbf,
               const int* __restrict__ rowptr, const int* __restrict__ csr_src,
               const float* __restrict__ csr_w, const float* __restrict__ dinv,
               void* __restrict__ hout, int outf32, int n) {
    int node = blockIdx.x * 4 + (threadIdx.x >> 6);
    int lane = threadIdx.x & 63;
    if (node >= n) return;
    prop_node(hin, zbf, rowptr, csr_src, csr_w, dinv, hout, outf32 != 0, node, lane);
}

// ==================================================================
extern "C" void kernel_launch(void* const* d_in, const int* in_sizes, int n_in,
                              void* d_out, int out_size, void* d_ws, size_t ws_size,
                              hipStream_t stream) {
    const float* x  = (const float*)d_in[0];
    const void*  ei = d_in[1];
    const float* W1 = (const float*)d_in[2];
    const float* b1 = (const float*)d_in[3];
    const float* W2 = (const float*)d_in[4];
    const float* b2 = (const float*)d_in[5];
    float* dout = (float*)d_out;

    const int IN_C = 512, HID_C = 256, OUT_C = 64;
    int N = in_sizes[0] / IN_C;   // 50000
    int E = in_sizes[1] / 2;      // 800000
    int Ksteps = 10;

    char* w = (char*)d_ws;
    auto alloc = [&](size_t bytes) { char* p = w; w += (bytes + 255) & ~(size_t)255; return p; };
    int*   flag    = (int*)  alloc(4);
    int*   src32   = (int*)  alloc((size_t)E * 4);
    int*   dst32   = (int*)  alloc((size_t)E * 4);
    int*   counts  = (int*)  alloc((size_t)N * 4);
    int*   rowptr  = (int*)  alloc((size_t)(N + 1) * 4);
    int*   cursor  = (int*)  alloc((size_t)N * 4);
    float* dinv    = (float*)alloc((size_t)N * 4);
    int*   csr_src = (int*)  alloc((size_t)E * 4);
    float* csr_w   = (float*)alloc((size_t)E * 4);
    short* W1h     = (short*)alloc((size_t)HID_C * IN_C * 2);
    short* W1l     = (short*)alloc((size_t)HID_C * IN_C * 2);
    short* W2h     = (short*)alloc((size_t)OUT_C * HID_C * 2);
    short* W2l     = (short*)alloc((size_t)OUT_C * HID_C * 2);
    short* xbf     = (short*)alloc((size_t)N * IN_C * 2);
    short* Hbf     = (short*)alloc((size_t)N * HID_C * 2);
    unsigned short* zbf = (unsigned short*)alloc((size_t)N * OUT_C * 2);
    unsigned short* hA  = (unsigned short*)alloc((size_t)N * OUT_C * 2);
    unsigned short* hB  = (unsigned short*)alloc((size_t)N * OUT_C * 2);
    int*   bs      = (int*)  alloc(256 * 4);
    int*   bsoff   = (int*)  alloc(256 * 4);

    int dev = 0;
    hipGetDevice(&dev);
    hipDeviceProp_t prop;
    bool coop_cap = (hipGetDeviceProperties(&prop, dev) == hipSuccess) && prop.cooperativeLaunch;
    int ncu = prop.multiProcessorCount > 0 ? prop.multiProcessorCount : 256;

    auto try_coop = [&](const void* f, int threads, int desired, void** args) -> bool {
        if (!coop_cap) return false;
        int occ = 0;
        if (hipOccupancyMaxActiveBlocksPerMultiprocessor(&occ, f, threads, 0) != hipSuccess || occ <= 0)
            return false;
        long cap = (long)occ * ncu;
        int g = (int)(desired < cap ? desired : cap);
        return hipLaunchCooperativeKernel(f, dim3(g), dim3(threads), args, 0, stream) == hipSuccess;
    };

    const int egrid = (E + 255) / 256;
    const int nblk = (N + 255) / 256;
    const int mgrid = (N + 127) / 128;
    const int pgrid = (N + 3) / 4;

    // ---------------- stage 1: preprocessing ----------------
    {
        void* args[] = {&x, &ei, &W1, &W2, &xbf, &W1h, &W1l, &W2h, &W2l,
                        &flag, &src32, &dst32, &counts, &dinv, &rowptr, &cursor,
                        &bs, &bsoff, &csr_src, &csr_w, &N, &E};
        if (!try_coop((const void*)pre_kernel, 256, 1024, args)) {
            hipMemsetAsync(flag, 0, 4, stream);
            hipMemsetAsync(counts, 0, (size_t)N * 4, stream);
            cvtbf_kernel<<<2048, 256, 0, stream>>>(x, xbf, N * IN_C / 8);
            wsplit_kernel<<<(HID_C * IN_C + 255) / 256, 256, 0, stream>>>(W1, W1h, W1l, HID_C * IN_C);
            wsplit_kernel<<<(OUT_C * HID_C + 255) / 256, 256, 0, stream>>>(W2, W2h, W2l, OUT_C * HID_C);
            detect_kernel<<<1, 256, 0, stream>>>((const unsigned int*)ei, flag);
            convert_count_kernel<<<egrid, 256, 0, stream>>>(ei, flag, src32, dst32, counts, E);
            dinv_kernel<<<nblk, 256, 0, stream>>>(counts, dinv, N);
            blocksum_kernel<<<nblk, 256, 0, stream>>>(counts, bs, N);
            scanbs_kernel<<<1, 256, 0, stream>>>(bs, bsoff, nblk);
            scanblock_kernel<<<nblk, 256, 0, stream>>>(counts, bsoff, rowptr, cursor, N);
            fill_kernel<<<egrid, 256, 0, stream>>>(src32, dst32, dinv, cursor, csr_src, csr_w, E);
        }
    }
    // ---------------- stage 2: MLP (GEMM1 + GEMM2) ----------------
    {
        void* args[] = {&xbf, &W1h, &W1l, &b1, &Hbf, &W2h, &W2l, &b2, &zbf, &N};
        if (!try_coop((const void*)gemm_fused, 512, 512, args)) {
            gemm1_k<<<mgrid * 4, 512, 0, stream>>>(xbf, W1h, W1l, b1, Hbf, N);
            gemm2_k<<<mgrid, 512, 0, stream>>>(Hbf, W2h, W2l, b2, (short*)zbf, N);
        }
    }
    // ---------------- stage 3: propagation (10 steps) ----------------
    {
        void* args[] = {&zbf, &hA, &hB, &rowptr, &csr_src, &csr_w, &dinv, &dout,
                        &N, &Ksteps};
        if (!try_coop((const void*)prop_fused, 256, 2048, args)) {
            const unsigned short* pin = zbf;
            for (int s = 0; s < Ksteps; ++s) {
                bool last = (s == Ksteps - 1);
                void* out = last ? (void*)dout : ((s & 1) ? (void*)hB : (void*)hA);
                prop_step<<<pgrid, 256, 0, stream>>>(pin, zbf, rowptr, csr_src, csr_w, dinv,
                                                     out, last ? 1 : 0, N);
                pin = (const unsigned short*)out;
            }
        }
    }
}

// Round 9
// 477.078 us; speedup vs baseline: 6.6265x; 6.6265x over previous
//
#include <hip/hip_runtime.h>

typedef __bf16 bf16x8 __attribute__((ext_vector_type(8)));
typedef float f32x4 __attribute__((ext_vector_type(4)));
typedef short short8 __attribute__((ext_vector_type(8)));

__device__ __forceinline__ unsigned short f2bf_u(float f) {
    unsigned u = __builtin_bit_cast(unsigned, f);
    u += 0x7FFFu + ((u >> 16) & 1u);   // RNE
    return (unsigned short)(u >> 16);
}
__device__ __forceinline__ float bf2f(unsigned short h) {
    unsigned u = ((unsigned)h) << 16;
    return __builtin_bit_cast(float, u);
}
__device__ __forceinline__ float i2f(int b) { return __builtin_bit_cast(float, b); }

#define GLOAD_LDS16(gsrc, ldst)                                                        \
    __builtin_amdgcn_global_load_lds((const __attribute__((address_space(1))) void*)(gsrc), \
                                     (__attribute__((address_space(3))) void*)(ldst), 16, 0, 0)

// ==================================================================
// Preprocessing (classic chain, proven round 6)
// ==================================================================
__global__ void detect_kernel(const unsigned int* __restrict__ edges, int* flag) {
    unsigned v = 0;
    for (int i = threadIdx.x * 2 + 1; i < 2048; i += 512) v |= edges[i];
    if (v) atomicOr(flag, 1);
}

__global__ void convert_count_kernel(const void* __restrict__ edges, const int* __restrict__ flag,
                                     int* __restrict__ src, int* __restrict__ dst,
                                     int* __restrict__ counts, int E) {
    int e = blockIdx.x * 256 + threadIdx.x;
    if (e >= E) return;
    int s, d;
    if (*flag) { const int* p = (const int*)edges; s = p[e]; d = p[E + e]; }
    else       { const long long* p = (const long long*)edges; s = (int)p[e]; d = (int)p[E + e]; }
    src[e] = s;
    dst[e] = d;
    atomicAdd(&counts[d], 1);
}

__global__ void dinv_kernel(const int* __restrict__ counts, float* __restrict__ dinv, int n) {
    int i = blockIdx.x * 256 + threadIdx.x;
    if (i < n) dinv[i] = rsqrtf((float)counts[i] + 1.0f);
}

__global__ void blocksum_kernel(const int* __restrict__ counts, int* __restrict__ bs, int n) {
    __shared__ int sdata[256];
    int i = blockIdx.x * 256 + threadIdx.x;
    sdata[threadIdx.x] = (i < n) ? counts[i] : 0;
    __syncthreads();
    #pragma unroll
    for (int off = 128; off > 0; off >>= 1) {
        if (threadIdx.x < off) sdata[threadIdx.x] += sdata[threadIdx.x + off];
        __syncthreads();
    }
    if (threadIdx.x == 0) bs[blockIdx.x] = sdata[0];
}

__global__ void scanbs_kernel(const int* __restrict__ bs, int* __restrict__ bsoff, int nb) {
    __shared__ int sdata[256];
    int tid = threadIdx.x;
    int v = (tid < nb) ? bs[tid] : 0;
    sdata[tid] = v;
    __syncthreads();
    #pragma unroll
    for (int off = 1; off < 256; off <<= 1) {
        int t = (tid >= off) ? sdata[tid - off] : 0;
        __syncthreads();
        sdata[tid] += t;
        __syncthreads();
    }
    if (tid < nb) bsoff[tid] = sdata[tid] - v;
}

__global__ void scanblock_kernel(const int* __restrict__ counts, const int* __restrict__ bsoff,
                                 int* __restrict__ rowptr, int* __restrict__ cursor, int n) {
    __shared__ int sdata[256];
    int tid = threadIdx.x;
    int i = blockIdx.x * 256 + tid;
    int v = (i < n) ? counts[i] : 0;
    sdata[tid] = v;
    __syncthreads();
    #pragma unroll
    for (int off = 1; off < 256; off <<= 1) {
        int t = (tid >= off) ? sdata[tid - off] : 0;
        __syncthreads();
        sdata[tid] += t;
        __syncthreads();
    }
    int excl = bsoff[blockIdx.x] + sdata[tid] - v;
    if (i < n) { rowptr[i] = excl; cursor[i] = excl; }
    if (i == n - 1) rowptr[n] = excl + v;
}

// fill packed CSR records {src, w-bits}
__global__ void fill_kernel(const int* __restrict__ src, const int* __restrict__ dst,
                            const float* __restrict__ dinv, int* __restrict__ cursor,
                            int2* __restrict__ csr, int E) {
    int e = blockIdx.x * 256 + threadIdx.x;
    if (e >= E) return;
    int s = src[e], d = dst[e];
    int pos = atomicAdd(&cursor[d], 1);
    float w = dinv[s] * dinv[d];
    csr[pos] = make_int2(s, __builtin_bit_cast(int, w));
}

__global__ void wsplit_kernel(const float* __restrict__ W, short* __restrict__ Wh,
                              short* __restrict__ Wl, int n) {
    int i = blockIdx.x * 256 + threadIdx.x;
    if (i >= n) return;
    float w = W[i];
    unsigned short h = f2bf_u(w);
    Wh[i] = (short)h;
    Wl[i] = (short)f2bf_u(w - bf2f(h));
}

__global__ __launch_bounds__(256)
void cvtbf_kernel(const float* __restrict__ x, short* __restrict__ out, int n8) {
    for (int i = blockIdx.x * 256 + threadIdx.x; i < n8; i += gridDim.x * 256) {
        const float4* p = reinterpret_cast<const float4*>(x + (size_t)i * 8);
        float4 v0 = p[0], v1 = p[1];
        short8 s;
        s[0] = (short)f2bf_u(v0.x); s[1] = (short)f2bf_u(v0.y);
        s[2] = (short)f2bf_u(v0.z); s[3] = (short)f2bf_u(v0.w);
        s[4] = (short)f2bf_u(v1.x); s[5] = (short)f2bf_u(v1.y);
        s[6] = (short)f2bf_u(v1.z); s[7] = (short)f2bf_u(v1.w);
        *reinterpret_cast<short8*>(out + (size_t)i * 8) = s;
    }
}

// ==================================================================
// Double-buffered MFMA GEMM tile (proven round 6): BM=128, BN=64, BK=64,
// 512 thr (8 waves 4x2), global_load_lds w=16, XOR-swizzle kg^(row&7),
// prefetch-ahead, one vmcnt(0)+s_barrier per K-step.
// ==================================================================
template<int KDIM, int LDC, bool RELU>
__device__ __forceinline__
void gemm_tile(const short* __restrict__ A, const short* __restrict__ Bh,
               const short* __restrict__ Bl, const float* __restrict__ bias,
               short* __restrict__ C, int M, int m0, int n0,
               short* sAp, short* sBp) {
    constexpr int NT = KDIM / 64;
    const int tid  = threadIdx.x;
    const int lane = tid & 63;
    const int wave = tid >> 6;
    const int wr = wave >> 1, wc = wave & 1;
    const int lr = lane & 15;
    const int lk = lane >> 4;
    const int l8r = lane >> 3;
    const int l8u = lane & 7;

    f32x4 acc[2][2];
    #pragma unroll
    for (int mi = 0; mi < 2; ++mi)
        #pragma unroll
        for (int ni = 0; ni < 2; ++ni) acc[mi][ni] = {0.f, 0.f, 0.f, 0.f};

    auto stage = [&](int buf, int k0) {
        #pragma unroll
        for (int p = 0; p < 2; ++p) {
            int row = p * 64 + wave * 8 + l8r;
            int grow = m0 + row; if (grow > M - 1) grow = M - 1;
            const short* s = A + (size_t)grow * KDIM + k0 + ((l8u ^ (row & 7)) << 3);
            GLOAD_LDS16(s, sAp + buf * 8192 + p * 4096 + wave * 512);
        }
        int row = wave * 8 + l8r;
        size_t goff = (size_t)(n0 + row) * KDIM + k0 + ((l8u ^ (row & 7)) << 3);
        GLOAD_LDS16(Bh + goff, sBp + (buf * 2 + 0) * 4096 + wave * 512);
        GLOAD_LDS16(Bl + goff, sBp + (buf * 2 + 1) * 4096 + wave * 512);
    };

    stage(0, 0);
    asm volatile("s_waitcnt vmcnt(0)" ::: "memory");
    __builtin_amdgcn_s_barrier();
    asm volatile("" ::: "memory");

    int cur = 0;
    #pragma unroll 1
    for (int t = 0; t < NT; ++t) {
        if (t + 1 < NT) stage(cur ^ 1, (t + 1) * 64);
        #pragma unroll
        for (int ks = 0; ks < 2; ++ks) {
            int kg = ks * 4 + lk;
            bf16x8 af[2], bhf[2], blf[2];
            #pragma unroll
            for (int mi = 0; mi < 2; ++mi) {
                int row = wr * 32 + mi * 16 + lr;
                af[mi] = *reinterpret_cast<const bf16x8*>(
                    &sAp[cur * 8192 + row * 64 + ((kg ^ (row & 7)) << 3)]);
            }
            #pragma unroll
            for (int ni = 0; ni < 2; ++ni) {
                int row = wc * 32 + ni * 16 + lr;
                int idx = row * 64 + ((kg ^ (row & 7)) << 3);
                bhf[ni] = *reinterpret_cast<const bf16x8*>(&sBp[(cur * 2 + 0) * 4096 + idx]);
                blf[ni] = *reinterpret_cast<const bf16x8*>(&sBp[(cur * 2 + 1) * 4096 + idx]);
            }
            #pragma unroll
            for (int mi = 0; mi < 2; ++mi)
                #pragma unroll
                for (int ni = 0; ni < 2; ++ni) {
                    acc[mi][ni] = __builtin_amdgcn_mfma_f32_16x16x32_bf16(af[mi], bhf[ni], acc[mi][ni], 0, 0, 0);
                    acc[mi][ni] = __builtin_amdgcn_mfma_f32_16x16x32_bf16(af[mi], blf[ni], acc[mi][ni], 0, 0, 0);
                }
        }
        asm volatile("s_waitcnt vmcnt(0)" ::: "memory");
        __builtin_amdgcn_s_barrier();
        asm volatile("" ::: "memory");
        cur ^= 1;
    }

    #pragma unroll
    for (int ni = 0; ni < 2; ++ni) {
        int col = n0 + wc * 32 + ni * 16 + lr;
        float bv = bias[col];
        #pragma unroll
        for (int mi = 0; mi < 2; ++mi) {
            #pragma unroll
            for (int r = 0; r < 4; ++r) {
                int row = m0 + wr * 32 + mi * 16 + lk * 4 + r;
                if (row < M) {
                    float v = acc[mi][ni][r] + bv;
                    if (RELU) v = fmaxf(v, 0.0f);
                    C[(size_t)row * LDC + col] = (short)f2bf_u(v);
                }
            }
        }
    }
}

__global__ __launch_bounds__(512)
void gemm1_k(const short* __restrict__ xbf, const short* __restrict__ W1h,
             const short* __restrict__ W1l, const float* __restrict__ b1,
             short* __restrict__ Hbf, int M) {
    __shared__ short sAp[2 * 128 * 64];
    __shared__ short sBp[2 * 2 * 64 * 64];
    int t = blockIdx.x;
    gemm_tile<512, 256, true>(xbf, W1h, W1l, b1, Hbf, M, (t >> 2) * 128, (t & 3) * 64, sAp, sBp);
}

__global__ __launch_bounds__(512)
void gemm2_k(const short* __restrict__ Hbf, const short* __restrict__ W2h,
             const short* __restrict__ W2l, const float* __restrict__ b2,
             short* __restrict__ zbf, int M) {
    __shared__ short sAp[2 * 128 * 64];
    __shared__ short sBp[2 * 2 * 64 * 64];
    gemm_tile<256, 64, false>(Hbf, W2h, W2l, b2, zbf, M, blockIdx.x * 128, 0, sAp, sBp);
}

// ==================================================================
// Propagation step v2: one wave per node, lane = channel.
// Packed CSR records (int2 {src, w}) -> one dwordx2 broadcast load/edge;
// 12-deep gather pipeline (kept under the 64-VGPR occupancy cliff;
// NO min-occupancy launch_bounds arg -- round-8 spill lesson).
// ==================================================================
__global__ __launch_bounds__(256)
void prop_step(const unsigned short* __restrict__ hin, const unsigned short* __restrict__ zbf,
               const int* __restrict__ rowptr, const int2* __restrict__ csr,
               const float* __restrict__ dinv, void* __restrict__ hout,
               int outf32, int n) {
    int node = blockIdx.x * 4 + (threadIdx.x >> 6);
    int lane = threadIdx.x & 63;
    if (node >= n) return;
    float di = dinv[node];
    int base = node << 6;
    float acc = bf2f(hin[base + lane]) * (di * di);
    int e = rowptr[node], e1 = rowptr[node + 1];

    for (; e + 12 <= e1; e += 12) {
        int2 r[12]; unsigned short v[12];
        #pragma unroll
        for (int j = 0; j < 12; ++j) r[j] = csr[e + j];
        #pragma unroll
        for (int j = 0; j < 12; ++j) v[j] = hin[((unsigned)r[j].x << 6) + lane];
        #pragma unroll
        for (int j = 0; j < 12; ++j) acc = fmaf(bf2f(v[j]), i2f(r[j].y), acc);
    }
    for (; e + 4 <= e1; e += 4) {
        int2 r[4]; unsigned short v[4];
        #pragma unroll
        for (int j = 0; j < 4; ++j) r[j] = csr[e + j];
        #pragma unroll
        for (int j = 0; j < 4; ++j) v[j] = hin[((unsigned)r[j].x << 6) + lane];
        #pragma unroll
        for (int j = 0; j < 4; ++j) acc = fmaf(bf2f(v[j]), i2f(r[j].y), acc);
    }
    for (; e < e1; ++e) {
        int2 r = csr[e];
        acc = fmaf(bf2f(hin[((unsigned)r.x << 6) + lane]), i2f(r.y), acc);
    }

    float res = 0.9f * acc + 0.1f * bf2f(zbf[base + lane]);
    if (outf32) ((float*)hout)[base + lane] = res;
    else        ((unsigned short*)hout)[base + lane] = f2bf_u(res);
}

// ==================================================================
extern "C" void kernel_launch(void* const* d_in, const int* in_sizes, int n_in,
                              void* d_out, int out_size, void* d_ws, size_t ws_size,
                              hipStream_t stream) {
    const float* x  = (const float*)d_in[0];
    const void*  ei = d_in[1];
    const float* W1 = (const float*)d_in[2];
    const float* b1 = (const float*)d_in[3];
    const float* W2 = (const float*)d_in[4];
    const float* b2 = (const float*)d_in[5];
    float* dout = (float*)d_out;

    const int IN_C = 512, HID_C = 256, OUT_C = 64, Ksteps = 10;
    const int N = in_sizes[0] / IN_C;   // 50000
    const int E = in_sizes[1] / 2;      // 800000

    char* w = (char*)d_ws;
    auto alloc = [&](size_t bytes) { char* p = w; w += (bytes + 255) & ~(size_t)255; return p; };
    int*   flag    = (int*)  alloc(4);
    int*   src32   = (int*)  alloc((size_t)E * 4);
    int*   dst32   = (int*)  alloc((size_t)E * 4);
    int*   counts  = (int*)  alloc((size_t)N * 4);
    int*   rowptr  = (int*)  alloc((size_t)(N + 1) * 4);
    int*   cursor  = (int*)  alloc((size_t)N * 4);
    float* dinv    = (float*)alloc((size_t)N * 4);
    int2*  csr     = (int2*) alloc((size_t)E * 8);
    short* W1h     = (short*)alloc((size_t)HID_C * IN_C * 2);
    short* W1l     = (short*)alloc((size_t)HID_C * IN_C * 2);
    short* W2h     = (short*)alloc((size_t)OUT_C * HID_C * 2);
    short* W2l     = (short*)alloc((size_t)OUT_C * HID_C * 2);
    short* xbf     = (short*)alloc((size_t)N * IN_C * 2);
    short* Hbf     = (short*)alloc((size_t)N * HID_C * 2);
    unsigned short* zbf = (unsigned short*)alloc((size_t)N * OUT_C * 2);
    unsigned short* hA  = (unsigned short*)alloc((size_t)N * OUT_C * 2);
    unsigned short* hB  = (unsigned short*)alloc((size_t)N * OUT_C * 2);
    int*   bs      = (int*)  alloc(256 * 4);
    int*   bsoff   = (int*)  alloc(256 * 4);

    hipMemsetAsync(flag, 0, 4, stream);
    hipMemsetAsync(counts, 0, (size_t)N * 4, stream);

    const int egrid = (E + 255) / 256;
    const int nblk = (N + 255) / 256;
    const int mgrid = (N + 127) / 128;
    const int pgrid = (N + 3) / 4;

    // preprocessing
    cvtbf_kernel<<<2048, 256, 0, stream>>>(x, xbf, N * IN_C / 8);
    wsplit_kernel<<<(HID_C * IN_C + 255) / 256, 256, 0, stream>>>(W1, W1h, W1l, HID_C * IN_C);
    wsplit_kernel<<<(OUT_C * HID_C + 255) / 256, 256, 0, stream>>>(W2, W2h, W2l, OUT_C * HID_C);
    detect_kernel<<<1, 256, 0, stream>>>((const unsigned int*)ei, flag);
    convert_count_kernel<<<egrid, 256, 0, stream>>>(ei, flag, src32, dst32, counts, E);
    dinv_kernel<<<nblk, 256, 0, stream>>>(counts, dinv, N);
    blocksum_kernel<<<nblk, 256, 0, stream>>>(counts, bs, N);
    scanbs_kernel<<<1, 256, 0, stream>>>(bs, bsoff, nblk);
    scanblock_kernel<<<nblk, 256, 0, stream>>>(counts, bsoff, rowptr, cursor, N);
    fill_kernel<<<egrid, 256, 0, stream>>>(src32, dst32, dinv, cursor, csr, E);

    // MLP (double-buffered DMA-staged MFMA)
    gemm1_k<<<mgrid * 4, 512, 0, stream>>>(xbf, W1h, W1l, b1, Hbf, N);
    gemm2_k<<<mgrid, 512, 0, stream>>>(Hbf, W2h, W2l, b2, (short*)zbf, N);

    // propagation: h^(0)=z in zbf; ping-pong hA/hB; last step writes fp32 dout
    const unsigned short* pin = zbf;
    for (int s = 0; s < Ksteps; ++s) {
        bool last = (s == Ksteps - 1);
        void* out = last ? (void*)dout : ((s & 1) ? (void*)hB : (void*)hA);
        prop_step<<<pgrid, 256, 0, stream>>>(pin, zbf, rowptr, csr, dinv,
                                             out, last ? 1 : 0, N);
        pin = (const unsigned short*)out;
    }
}

// Round 10
// 473.745 us; speedup vs baseline: 6.6731x; 1.0070x over previous
//
#include <hip/hip_runtime.h>

typedef __bf16 bf16x8 __attribute__((ext_vector_type(8)));
typedef float f32x4 __attribute__((ext_vector_type(4)));
typedef short short8 __attribute__((ext_vector_type(8)));

__device__ __forceinline__ unsigned short f2bf_u(float f) {
    unsigned u = __builtin_bit_cast(unsigned, f);
    u += 0x7FFFu + ((u >> 16) & 1u);   // RNE
    return (unsigned short)(u >> 16);
}
__device__ __forceinline__ float bf2f(unsigned short h) {
    unsigned u = ((unsigned)h) << 16;
    return __builtin_bit_cast(float, u);
}
__device__ __forceinline__ float i2f(int b) { return __builtin_bit_cast(float, b); }

#define GLOAD_LDS16(gsrc, ldst)                                                        \
    __builtin_amdgcn_global_load_lds((const __attribute__((address_space(1))) void*)(gsrc), \
                                     (__attribute__((address_space(3))) void*)(ldst), 16, 0, 0)

// ==================================================================
// prep_a: edge dtype detect (block 0) + both weight splits. Grid-stride.
// ==================================================================
__global__ __launch_bounds__(256)
void prep_a(const void* __restrict__ ei, const float* __restrict__ W1,
            const float* __restrict__ W2, int* __restrict__ flag,
            short* __restrict__ W1h, short* __restrict__ W1l,
            short* __restrict__ W2h, short* __restrict__ W2l) {
    const int tid = threadIdx.x;
    const int gtid = blockIdx.x * 256 + tid;
    const int gsize = gridDim.x * 256;
    if (blockIdx.x == 0) {
        unsigned v = 0;
        for (int i = tid * 2 + 1; i < 2048; i += 512) v |= ((const unsigned*)ei)[i];
        if (v) atomicOr(flag, 1);
    }
    const int n1 = 256 * 512, n2 = 64 * 256;
    for (int i = gtid; i < n1; i += gsize) {
        float w0 = W1[i];
        unsigned short h = f2bf_u(w0);
        W1h[i] = (short)h;
        W1l[i] = (short)f2bf_u(w0 - bf2f(h));
    }
    for (int i = gtid; i < n2; i += gsize) {
        float w0 = W2[i];
        unsigned short h = f2bf_u(w0);
        W2h[i] = (short)h;
        W2l[i] = (short)f2bf_u(w0 - bf2f(h));
    }
}

__global__ void convert_count_kernel(const void* __restrict__ edges, const int* __restrict__ flag,
                                     int* __restrict__ src, int* __restrict__ dst,
                                     int* __restrict__ counts, int E) {
    int e = blockIdx.x * 256 + threadIdx.x;
    if (e >= E) return;
    int s, d;
    if (*flag) { const int* p = (const int*)edges; s = p[e]; d = p[E + e]; }
    else       { const long long* p = (const long long*)edges; s = (int)p[e]; d = (int)p[E + e]; }
    src[e] = s;
    dst[e] = d;
    atomicAdd(&counts[d], 1);
}

// per-chunk: dinv + block-sum reduce (fused)
__global__ void bsum_dinv_kernel(const int* __restrict__ counts, float* __restrict__ dinv,
                                 int* __restrict__ bs, int n) {
    __shared__ int sdata[256];
    int i = blockIdx.x * 256 + threadIdx.x;
    int v = (i < n) ? counts[i] : 0;
    if (i < n) dinv[i] = rsqrtf((float)v + 1.0f);
    sdata[threadIdx.x] = v;
    __syncthreads();
    #pragma unroll
    for (int off = 128; off > 0; off >>= 1) {
        if (threadIdx.x < off) sdata[threadIdx.x] += sdata[threadIdx.x + off];
        __syncthreads();
    }
    if (threadIdx.x == 0) bs[blockIdx.x] = sdata[0];
}

__global__ void scanbs_kernel(const int* __restrict__ bs, int* __restrict__ bsoff, int nb) {
    __shared__ int sdata[256];
    int tid = threadIdx.x;
    int v = (tid < nb) ? bs[tid] : 0;
    sdata[tid] = v;
    __syncthreads();
    #pragma unroll
    for (int off = 1; off < 256; off <<= 1) {
        int t = (tid >= off) ? sdata[tid - off] : 0;
        __syncthreads();
        sdata[tid] += t;
        __syncthreads();
    }
    if (tid < nb) bsoff[tid] = sdata[tid] - v;
}

__global__ void scanblock_kernel(const int* __restrict__ counts, const int* __restrict__ bsoff,
                                 int* __restrict__ rowptr, int* __restrict__ cursor, int n) {
    __shared__ int sdata[256];
    int tid = threadIdx.x;
    int i = blockIdx.x * 256 + tid;
    int v = (i < n) ? counts[i] : 0;
    sdata[tid] = v;
    __syncthreads();
    #pragma unroll
    for (int off = 1; off < 256; off <<= 1) {
        int t = (tid >= off) ? sdata[tid - off] : 0;
        __syncthreads();
        sdata[tid] += t;
        __syncthreads();
    }
    int excl = bsoff[blockIdx.x] + sdata[tid] - v;
    if (i < n) { rowptr[i] = excl; cursor[i] = excl; }
    if (i == n - 1) rowptr[n] = excl + v;
}

__global__ void fill_kernel(const int* __restrict__ src, const int* __restrict__ dst,
                            const float* __restrict__ dinv, int* __restrict__ cursor,
                            int2* __restrict__ csr, int E) {
    int e = blockIdx.x * 256 + threadIdx.x;
    if (e >= E) return;
    int s = src[e], d = dst[e];
    int pos = atomicAdd(&cursor[d], 1);
    float w = dinv[s] * dinv[d];
    csr[pos] = make_int2(s, __builtin_bit_cast(int, w));
}

// ==================================================================
// Double-buffered MFMA GEMM tile. BM=128, BN=64, BK=64, 512 thr (8 waves 4x2),
// XOR-swizzle kg^(row&7), prefetch-ahead, one sync per K-step.
// AF32=true: A is fp32, reg-staged with fused RNE cvt (T14 split:
//   issue loads(t+1) -> compute(t) -> vmcnt(0) -> cvt+ds_write -> syncthreads).
// AF32=false: A bf16 via global_load_lds (proven r6 path).
// ==================================================================
template<int KDIM, int LDC, bool AF32, bool RELU>
__device__ __forceinline__
void gemm_tile(const void* __restrict__ Av, const short* __restrict__ Bh,
               const short* __restrict__ Bl, const float* __restrict__ bias,
               short* __restrict__ C, int M, int m0, int n0,
               short* sAp, short* sBp) {
    constexpr int NT = KDIM / 64;
    const int tid  = threadIdx.x;
    const int lane = tid & 63;
    const int wave = tid >> 6;
    const int wr = wave >> 1, wc = wave & 1;
    const int lr = lane & 15;
    const int lk = lane >> 4;
    const int l8r = lane >> 3;
    const int l8u = lane & 7;
    const int tr = tid >> 3;          // 0..63 (A fp32 staging row)
    const int tk = tid & 7;           // 16B-unit / 8-fp32 group

    f32x4 acc[2][2];
    #pragma unroll
    for (int mi = 0; mi < 2; ++mi)
        #pragma unroll
        for (int ni = 0; ni < 2; ++ni) acc[mi][ni] = {0.f, 0.f, 0.f, 0.f};

    float4 fa[2][2];   // in-flight fp32 A fragments (AF32 path)

    auto a_load = [&](int k0) {       // issue global loads for A tile (fp32)
        #pragma unroll
        for (int p = 0; p < 2; ++p) {
            int row = p * 64 + tr;
            int grow = m0 + row; if (grow > M - 1) grow = M - 1;
            const float* s = (const float*)Av + (size_t)grow * KDIM + k0 + tk * 8;
            fa[p][0] = *reinterpret_cast<const float4*>(s);
            fa[p][1] = *reinterpret_cast<const float4*>(s + 4);
        }
    };
    auto a_write = [&](int buf) {     // cvt + swizzled ds_write_b128
        #pragma unroll
        for (int p = 0; p < 2; ++p) {
            int row = p * 64 + tr;
            short8 sh;
            sh[0] = (short)f2bf_u(fa[p][0].x); sh[1] = (short)f2bf_u(fa[p][0].y);
            sh[2] = (short)f2bf_u(fa[p][0].z); sh[3] = (short)f2bf_u(fa[p][0].w);
            sh[4] = (short)f2bf_u(fa[p][1].x); sh[5] = (short)f2bf_u(fa[p][1].y);
            sh[6] = (short)f2bf_u(fa[p][1].z); sh[7] = (short)f2bf_u(fa[p][1].w);
            *reinterpret_cast<short8*>(&sAp[buf * 8192 + row * 64 + ((tk ^ (row & 7)) << 3)]) = sh;
        }
    };
    auto a_dma = [&](int buf, int k0) {   // bf16 A via async DMA
        #pragma unroll
        for (int p = 0; p < 2; ++p) {
            int row = p * 64 + wave * 8 + l8r;
            int grow = m0 + row; if (grow > M - 1) grow = M - 1;
            const short* s = (const short*)Av + (size_t)grow * KDIM + k0 + ((l8u ^ (row & 7)) << 3);
            GLOAD_LDS16(s, sAp + buf * 8192 + p * 4096 + wave * 512);
        }
    };
    auto b_dma = [&](int buf, int k0) {
        int row = wave * 8 + l8r;
        size_t goff = (size_t)(n0 + row) * KDIM + k0 + ((l8u ^ (row & 7)) << 3);
        GLOAD_LDS16(Bh + goff, sBp + (buf * 2 + 0) * 4096 + wave * 512);
        GLOAD_LDS16(Bl + goff, sBp + (buf * 2 + 1) * 4096 + wave * 512);
    };

    // prologue: stage tile 0 into buf 0
    if (AF32) {
        a_load(0);
        b_dma(0, 0);
        asm volatile("s_waitcnt vmcnt(0)" ::: "memory");
        a_write(0);
        __syncthreads();
    } else {
        a_dma(0, 0);
        b_dma(0, 0);
        asm volatile("s_waitcnt vmcnt(0)" ::: "memory");
        __builtin_amdgcn_s_barrier();
        asm volatile("" ::: "memory");
    }

    int cur = 0;
    #pragma unroll 1
    for (int t = 0; t < NT; ++t) {
        const bool pf = (t + 1 < NT);
        if (pf) {                       // issue next-tile loads before compute
            if (AF32) a_load((t + 1) * 64);
            else      a_dma(cur ^ 1, (t + 1) * 64);
            b_dma(cur ^ 1, (t + 1) * 64);
        }
        #pragma unroll
        for (int ks = 0; ks < 2; ++ks) {
            int kg = ks * 4 + lk;
            bf16x8 af[2], bhf[2], blf[2];
            #pragma unroll
            for (int mi = 0; mi < 2; ++mi) {
                int row = wr * 32 + mi * 16 + lr;
                af[mi] = *reinterpret_cast<const bf16x8*>(
                    &sAp[cur * 8192 + row * 64 + ((kg ^ (row & 7)) << 3)]);
            }
            #pragma unroll
            for (int ni = 0; ni < 2; ++ni) {
                int row = wc * 32 + ni * 16 + lr;
                int idx = row * 64 + ((kg ^ (row & 7)) << 3);
                bhf[ni] = *reinterpret_cast<const bf16x8*>(&sBp[(cur * 2 + 0) * 4096 + idx]);
                blf[ni] = *reinterpret_cast<const bf16x8*>(&sBp[(cur * 2 + 1) * 4096 + idx]);
            }
            #pragma unroll
            for (int mi = 0; mi < 2; ++mi)
                #pragma unroll
                for (int ni = 0; ni < 2; ++ni) {
                    acc[mi][ni] = __builtin_amdgcn_mfma_f32_16x16x32_bf16(af[mi], bhf[ni], acc[mi][ni], 0, 0, 0);
                    acc[mi][ni] = __builtin_amdgcn_mfma_f32_16x16x32_bf16(af[mi], blf[ni], acc[mi][ni], 0, 0, 0);
                }
        }
        if (AF32) {
            asm volatile("s_waitcnt vmcnt(0)" ::: "memory");   // A regs + B DMA landed
            if (pf) a_write(cur ^ 1);
            __syncthreads();                                    // drains lgkm (ds_write visible)
        } else {
            asm volatile("s_waitcnt vmcnt(0)" ::: "memory");
            __builtin_amdgcn_s_barrier();
            asm volatile("" ::: "memory");
        }
        cur ^= 1;
    }

    // epilogue
    #pragma unroll
    for (int ni = 0; ni < 2; ++ni) {
        int col = n0 + wc * 32 + ni * 16 + lr;
        float bv = bias[col];
        #pragma unroll
        for (int mi = 0; mi < 2; ++mi) {
            #pragma unroll
            for (int r = 0; r < 4; ++r) {
                int row = m0 + wr * 32 + mi * 16 + lk * 4 + r;
                if (row < M) {
                    float v = acc[mi][ni][r] + bv;
                    if (RELU) v = fmaxf(v, 0.0f);
                    C[(size_t)row * LDC + col] = (short)f2bf_u(v);
                }
            }
        }
    }
}

__global__ __launch_bounds__(512)
void gemm1_k(const float* __restrict__ x, const short* __restrict__ W1h,
             const short* __restrict__ W1l, const float* __restrict__ b1,
             short* __restrict__ Hbf, int M) {
    __shared__ short sAp[2 * 128 * 64];
    __shared__ short sBp[2 * 2 * 64 * 64];
    int t = blockIdx.x;
    gemm_tile<512, 256, true, true>(x, W1h, W1l, b1, Hbf, M, (t >> 2) * 128, (t & 3) * 64, sAp, sBp);
}

__global__ __launch_bounds__(512)
void gemm2_k(const short* __restrict__ Hbf, const short* __restrict__ W2h,
             const short* __restrict__ W2l, const float* __restrict__ b2,
             short* __restrict__ zbf, int M) {
    __shared__ short sAp[2 * 128 * 64];
    __shared__ short sBp[2 * 2 * 64 * 64];
    gemm_tile<256, 64, false, false>(Hbf, W2h, W2l, b2, zbf, M, blockIdx.x * 128, 0, sAp, sBp);
}

// ==================================================================
// Propagation step (proven r9): one wave per node, lane = channel.
// Packed CSR int2 {src, w}; 12-deep gather pipeline; no min-occupancy bound.
// ==================================================================
__global__ __launch_bounds__(256)
void prop_step(const unsigned short* __restrict__ hin, const unsigned short* __restrict__ zbf,
               const int* __restrict__ rowptr, const int2* __restrict__ csr,
               const float* __restrict__ dinv, void* __restrict__ hout,
               int outf32, int n) {
    int node = blockIdx.x * 4 + (threadIdx.x >> 6);
    int lane = threadIdx.x & 63;
    if (node >= n) return;
    float di = dinv[node];
    int base = node << 6;
    float acc = bf2f(hin[base + lane]) * (di * di);
    int e = rowptr[node], e1 = rowptr[node + 1];

    for (; e + 12 <= e1; e += 12) {
        int2 r[12]; unsigned short v[12];
        #pragma unroll
        for (int j = 0; j < 12; ++j) r[j] = csr[e + j];
        #pragma unroll
        for (int j = 0; j < 12; ++j) v[j] = hin[((unsigned)r[j].x << 6) + lane];
        #pragma unroll
        for (int j = 0; j < 12; ++j) acc = fmaf(bf2f(v[j]), i2f(r[j].y), acc);
    }
    for (; e + 4 <= e1; e += 4) {
        int2 r[4]; unsigned short v[4];
        #pragma unroll
        for (int j = 0; j < 4; ++j) r[j] = csr[e + j];
        #pragma unroll
        for (int j = 0; j < 4; ++j) v[j] = hin[((unsigned)r[j].x << 6) + lane];
        #pragma unroll
        for (int j = 0; j < 4; ++j) acc = fmaf(bf2f(v[j]), i2f(r[j].y), acc);
    }
    for (; e < e1; ++e) {
        int2 r = csr[e];
        acc = fmaf(bf2f(hin[((unsigned)r.x << 6) + lane]), i2f(r.y), acc);
    }

    float res = 0.9f * acc + 0.1f * bf2f(zbf[base + lane]);
    if (outf32) ((float*)hout)[base + lane] = res;
    else        ((unsigned short*)hout)[base + lane] = f2bf_u(res);
}

// ==================================================================
extern "C" void kernel_launch(void* const* d_in, const int* in_sizes, int n_in,
                              void* d_out, int out_size, void* d_ws, size_t ws_size,
                              hipStream_t stream) {
    const float* x  = (const float*)d_in[0];
    const void*  ei = d_in[1];
    const float* W1 = (const float*)d_in[2];
    const float* b1 = (const float*)d_in[3];
    const float* W2 = (const float*)d_in[4];
    const float* b2 = (const float*)d_in[5];
    float* dout = (float*)d_out;

    const int IN_C = 512, HID_C = 256, OUT_C = 64, Ksteps = 10;
    const int N = in_sizes[0] / IN_C;   // 50000
    const int E = in_sizes[1] / 2;      // 800000

    char* w = (char*)d_ws;
    auto alloc = [&](size_t bytes) { char* p = w; w += (bytes + 255) & ~(size_t)255; return p; };
    int*   flag    = (int*)  alloc(4);
    int*   src32   = (int*)  alloc((size_t)E * 4);
    int*   dst32   = (int*)  alloc((size_t)E * 4);
    int*   counts  = (int*)  alloc((size_t)N * 4);
    int*   rowptr  = (int*)  alloc((size_t)(N + 1) * 4);
    int*   cursor  = (int*)  alloc((size_t)N * 4);
    float* dinv    = (float*)alloc((size_t)N * 4);
    int2*  csr     = (int2*) alloc((size_t)E * 8);
    short* W1h     = (short*)alloc((size_t)HID_C * IN_C * 2);
    short* W1l     = (short*)alloc((size_t)HID_C * IN_C * 2);
    short* W2h     = (short*)alloc((size_t)OUT_C * HID_C * 2);
    short* W2l     = (short*)alloc((size_t)OUT_C * HID_C * 2);
    short* Hbf     = (short*)alloc((size_t)N * HID_C * 2);
    unsigned short* zbf = (unsigned short*)alloc((size_t)N * OUT_C * 2);
    unsigned short* hA  = (unsigned short*)alloc((size_t)N * OUT_C * 2);
    unsigned short* hB  = (unsigned short*)alloc((size_t)N * OUT_C * 2);
    int*   bs      = (int*)  alloc(256 * 4);
    int*   bsoff   = (int*)  alloc(256 * 4);

    hipMemsetAsync(flag, 0, 4, stream);
    hipMemsetAsync(counts, 0, (size_t)N * 4, stream);

    const int egrid = (E + 255) / 256;
    const int nblk = (N + 255) / 256;
    const int mgrid = (N + 127) / 128;
    const int pgrid = (N + 3) / 4;

    // preprocessing (fused: 6 dispatches)
    prep_a<<<512, 256, 0, stream>>>(ei, W1, W2, flag, W1h, W1l, W2h, W2l);
    convert_count_kernel<<<egrid, 256, 0, stream>>>(ei, flag, src32, dst32, counts, E);
    bsum_dinv_kernel<<<nblk, 256, 0, stream>>>(counts, dinv, bs, N);
    scanbs_kernel<<<1, 256, 0, stream>>>(bs, bsoff, nblk);
    scanblock_kernel<<<nblk, 256, 0, stream>>>(counts, bsoff, rowptr, cursor, N);
    fill_kernel<<<egrid, 256, 0, stream>>>(src32, dst32, dinv, cursor, csr, E);

    // MLP: gemm1 reads x fp32 directly (fused cvt), gemm2 on bf16 H
    gemm1_k<<<mgrid * 4, 512, 0, stream>>>(x, W1h, W1l, b1, Hbf, N);
    gemm2_k<<<mgrid, 512, 0, stream>>>(Hbf, W2h, W2l, b2, (short*)zbf, N);

    // propagation: h^(0)=z in zbf; ping-pong hA/hB; last step writes fp32 dout
    const unsigned short* pin = zbf;
    for (int s = 0; s < Ksteps; ++s) {
        bool last = (s == Ksteps - 1);
        void* out = last ? (void*)dout : ((s & 1) ? (void*)hB : (void*)hA);
        prop_step<<<pgrid, 256, 0, stream>>>(pin, zbf, rowptr, csr, dinv,
                                             out, last ? 1 : 0, N);
        pin = (const unsigned short*)out;
    }
}

// Round 11
// 452.094 us; speedup vs baseline: 6.9927x; 1.0479x over previous
//
#include <hip/hip_runtime.h>

typedef __bf16 bf16x8 __attribute__((ext_vector_type(8)));
typedef float f32x4 __attribute__((ext_vector_type(4)));
typedef short short8 __attribute__((ext_vector_type(8)));

__device__ __forceinline__ unsigned short f2bf_u(float f) {
    unsigned u = __builtin_bit_cast(unsigned, f);
    u += 0x7FFFu + ((u >> 16) & 1u);   // RNE
    return (unsigned short)(u >> 16);
}
__device__ __forceinline__ float bf2f(unsigned short h) {
    unsigned u = ((unsigned)h) << 16;
    return __builtin_bit_cast(float, u);
}
__device__ __forceinline__ float i2f(int b) { return __builtin_bit_cast(float, b); }

#define GLOAD_LDS16(gsrc, ldst)                                                        \
    __builtin_amdgcn_global_load_lds((const __attribute__((address_space(1))) void*)(gsrc), \
                                     (__attribute__((address_space(3))) void*)(ldst), 16, 0, 0)

// ==================================================================
// prep_a: edge dtype detect (block 0) + both weight splits. Grid-stride.
// ==================================================================
__global__ __launch_bounds__(256)
void prep_a(const void* __restrict__ ei, const float* __restrict__ W1,
            const float* __restrict__ W2, int* __restrict__ flag,
            short* __restrict__ W1h, short* __restrict__ W1l,
            short* __restrict__ W2h, short* __restrict__ W2l) {
    const int tid = threadIdx.x;
    const int gtid = blockIdx.x * 256 + tid;
    const int gsize = gridDim.x * 256;
    if (blockIdx.x == 0) {
        unsigned v = 0;
        for (int i = tid * 2 + 1; i < 2048; i += 512) v |= ((const unsigned*)ei)[i];
        if (v) atomicOr(flag, 1);
    }
    const int n1 = 256 * 512, n2 = 64 * 256;
    for (int i = gtid; i < n1; i += gsize) {
        float w0 = W1[i];
        unsigned short h = f2bf_u(w0);
        W1h[i] = (short)h;
        W1l[i] = (short)f2bf_u(w0 - bf2f(h));
    }
    for (int i = gtid; i < n2; i += gsize) {
        float w0 = W2[i];
        unsigned short h = f2bf_u(w0);
        W2h[i] = (short)h;
        W2l[i] = (short)f2bf_u(w0 - bf2f(h));
    }
}

__global__ void convert_count_kernel(const void* __restrict__ edges, const int* __restrict__ flag,
                                     int* __restrict__ src, int* __restrict__ dst,
                                     int* __restrict__ counts, int E) {
    int e = blockIdx.x * 256 + threadIdx.x;
    if (e >= E) return;
    int s, d;
    if (*flag) { const int* p = (const int*)edges; s = p[e]; d = p[E + e]; }
    else       { const long long* p = (const long long*)edges; s = (int)p[e]; d = (int)p[E + e]; }
    src[e] = s;
    dst[e] = d;
    atomicAdd(&counts[d], 1);
}

__global__ void bsum_dinv_kernel(const int* __restrict__ counts, float* __restrict__ dinv,
                                 int* __restrict__ bs, int n) {
    __shared__ int sdata[256];
    int i = blockIdx.x * 256 + threadIdx.x;
    int v = (i < n) ? counts[i] : 0;
    if (i < n) dinv[i] = rsqrtf((float)v + 1.0f);
    sdata[threadIdx.x] = v;
    __syncthreads();
    #pragma unroll
    for (int off = 128; off > 0; off >>= 1) {
        if (threadIdx.x < off) sdata[threadIdx.x] += sdata[threadIdx.x + off];
        __syncthreads();
    }
    if (threadIdx.x == 0) bs[blockIdx.x] = sdata[0];
}

__global__ void scanbs_kernel(const int* __restrict__ bs, int* __restrict__ bsoff, int nb) {
    __shared__ int sdata[256];
    int tid = threadIdx.x;
    int v = (tid < nb) ? bs[tid] : 0;
    sdata[tid] = v;
    __syncthreads();
    #pragma unroll
    for (int off = 1; off < 256; off <<= 1) {
        int t = (tid >= off) ? sdata[tid - off] : 0;
        __syncthreads();
        sdata[tid] += t;
        __syncthreads();
    }
    if (tid < nb) bsoff[tid] = sdata[tid] - v;
}

__global__ void scanblock_kernel(const int* __restrict__ counts, const int* __restrict__ bsoff,
                                 int* __restrict__ rowptr, int* __restrict__ cursor, int n) {
    __shared__ int sdata[256];
    int tid = threadIdx.x;
    int i = blockIdx.x * 256 + tid;
    int v = (i < n) ? counts[i] : 0;
    sdata[tid] = v;
    __syncthreads();
    #pragma unroll
    for (int off = 1; off < 256; off <<= 1) {
        int t = (tid >= off) ? sdata[tid - off] : 0;
        __syncthreads();
        sdata[tid] += t;
        __syncthreads();
    }
    int excl = bsoff[blockIdx.x] + sdata[tid] - v;
    if (i < n) { rowptr[i] = excl; cursor[i] = excl; }
    if (i == n - 1) rowptr[n] = excl + v;
}

__global__ void fill_kernel(const int* __restrict__ src, const int* __restrict__ dst,
                            const float* __restrict__ dinv, int* __restrict__ cursor,
                            int2* __restrict__ csr, int E) {
    int e = blockIdx.x * 256 + threadIdx.x;
    if (e >= E) return;
    int s = src[e], d = dst[e];
    int pos = atomicAdd(&cursor[d], 1);
    float w = dinv[s] * dinv[d];
    csr[pos] = make_int2(s, __builtin_bit_cast(int, w));
}

// ==================================================================
// gemm1f: BM=128, BN=256 (full width), BK=64, 512 thr (8 waves, 2m x 4n),
// dynamic LDS 160 KB (A dbuf 32K + Bh dbuf 64K + Bl dbuf 64K).
// A fp32 reg-staged + fused RNE cvt; B via global_load_lds; XOR swizzle
// kg^(row&7); prefetch-ahead; one vmcnt(0)+syncthreads per K-step.
// A is fetched from HBM exactly once (no n-tile refetch).
// ==================================================================
__global__ __launch_bounds__(512)
void gemm1f_k(const float* __restrict__ x, const short* __restrict__ Bh,
              const short* __restrict__ Bl, const float* __restrict__ bias,
              short* __restrict__ C, int M) {
    extern __shared__ short lds[];
    short* sA  = lds;              // [2][128*64]
    short* sBh = lds + 16384;      // [2][256*64]
    short* sBl = lds + 49152;      // [2][256*64]
    const int KDIM = 512, LDC = 256;
    const int tid = threadIdx.x, lane = tid & 63, wave = tid >> 6;
    const int wr = wave >> 2, wc = wave & 3;           // 2m x 4n
    const int m0 = blockIdx.x * 128;
    const int lr = lane & 15, lk = lane >> 4;
    const int l8r = lane >> 3, l8u = lane & 7;
    const int tr = tid >> 3, tk = tid & 7;

    f32x4 acc[4][4];
    #pragma unroll
    for (int mi = 0; mi < 4; ++mi)
        #pragma unroll
        for (int ni = 0; ni < 4; ++ni) acc[mi][ni] = {0.f, 0.f, 0.f, 0.f};

    float4 fa[2][2];

    auto a_load = [&](int k0) {
        #pragma unroll
        for (int p = 0; p < 2; ++p) {
            int row = p * 64 + tr;
            int grow = m0 + row; if (grow > M - 1) grow = M - 1;
            const float* s = x + (size_t)grow * KDIM + k0 + tk * 8;
            fa[p][0] = *reinterpret_cast<const float4*>(s);
            fa[p][1] = *reinterpret_cast<const float4*>(s + 4);
        }
    };
    auto a_write = [&](int buf) {
        #pragma unroll
        for (int p = 0; p < 2; ++p) {
            int row = p * 64 + tr;
            short8 sh;
            sh[0] = (short)f2bf_u(fa[p][0].x); sh[1] = (short)f2bf_u(fa[p][0].y);
            sh[2] = (short)f2bf_u(fa[p][0].z); sh[3] = (short)f2bf_u(fa[p][0].w);
            sh[4] = (short)f2bf_u(fa[p][1].x); sh[5] = (short)f2bf_u(fa[p][1].y);
            sh[6] = (short)f2bf_u(fa[p][1].z); sh[7] = (short)f2bf_u(fa[p][1].w);
            *reinterpret_cast<short8*>(&sA[buf * 8192 + row * 64 + ((tk ^ (row & 7)) << 3)]) = sh;
        }
    };
    auto b_dma = [&](int buf, int k0) {
        #pragma unroll
        for (int p = 0; p < 4; ++p) {
            int row = p * 64 + wave * 8 + l8r;
            size_t goff = (size_t)row * KDIM + k0 + ((l8u ^ (row & 7)) << 3);
            GLOAD_LDS16(Bh + goff, sBh + buf * 16384 + (p * 64 + wave * 8) * 64);
            GLOAD_LDS16(Bl + goff, sBl + buf * 16384 + (p * 64 + wave * 8) * 64);
        }
    };

    a_load(0);
    b_dma(0, 0);
    asm volatile("s_waitcnt vmcnt(0)" ::: "memory");
    a_write(0);
    __syncthreads();

    int cur = 0;
    #pragma unroll 1
    for (int t = 0; t < 8; ++t) {
        const bool pf = (t < 7);
        if (pf) {
            a_load((t + 1) * 64);
            b_dma(cur ^ 1, (t + 1) * 64);
        }
        #pragma unroll
        for (int ks = 0; ks < 2; ++ks) {
            int kg = ks * 4 + lk;
            bf16x8 af[4], bhf[4], blf[4];
            #pragma unroll
            for (int mi = 0; mi < 4; ++mi) {
                int row = wr * 64 + mi * 16 + lr;
                af[mi] = *reinterpret_cast<const bf16x8*>(
                    &sA[cur * 8192 + row * 64 + ((kg ^ (row & 7)) << 3)]);
            }
            #pragma unroll
            for (int ni = 0; ni < 4; ++ni) {
                int row = wc * 64 + ni * 16 + lr;
                int idx = cur * 16384 + row * 64 + ((kg ^ (row & 7)) << 3);
                bhf[ni] = *reinterpret_cast<const bf16x8*>(&sBh[idx]);
                blf[ni] = *reinterpret_cast<const bf16x8*>(&sBl[idx]);
            }
            #pragma unroll
            for (int mi = 0; mi < 4; ++mi)
                #pragma unroll
                for (int ni = 0; ni < 4; ++ni) {
                    acc[mi][ni] = __builtin_amdgcn_mfma_f32_16x16x32_bf16(af[mi], bhf[ni], acc[mi][ni], 0, 0, 0);
                    acc[mi][ni] = __builtin_amdgcn_mfma_f32_16x16x32_bf16(af[mi], blf[ni], acc[mi][ni], 0, 0, 0);
                }
        }
        asm volatile("s_waitcnt vmcnt(0)" ::: "memory");
        if (pf) a_write(cur ^ 1);
        __syncthreads();
        cur ^= 1;
    }

    #pragma unroll
    for (int ni = 0; ni < 4; ++ni) {
        int col = wc * 64 + ni * 16 + lr;
        float bv = bias[col];
        #pragma unroll
        for (int mi = 0; mi < 4; ++mi) {
            #pragma unroll
            for (int r = 0; r < 4; ++r) {
                int row = m0 + wr * 64 + mi * 16 + lk * 4 + r;
                if (row < M) {
                    float v = fmaxf(acc[mi][ni][r] + bv, 0.0f);
                    C[(size_t)row * LDC + col] = (short)f2bf_u(v);
                }
            }
        }
    }
}

// ==================================================================
// Fallback / gemm2 tile (r10, proven). BM=128, BN=64, BK=64, 8 waves 4x2.
// ==================================================================
template<int KDIM, int LDC, bool AF32, bool RELU>
__device__ __forceinline__
void gemm_tile(const void* __restrict__ Av, const short* __restrict__ Bh,
               const short* __restrict__ Bl, const float* __restrict__ bias,
               short* __restrict__ C, int M, int m0, int n0,
               short* sAp, short* sBp) {
    constexpr int NT = KDIM / 64;
    const int tid  = threadIdx.x;
    const int lane = tid & 63;
    const int wave = tid >> 6;
    const int wr = wave >> 1, wc = wave & 1;
    const int lr = lane & 15;
    const int lk = lane >> 4;
    const int l8r = lane >> 3;
    const int l8u = lane & 7;
    const int tr = tid >> 3;
    const int tk = tid & 7;

    f32x4 acc[2][2];
    #pragma unroll
    for (int mi = 0; mi < 2; ++mi)
        #pragma unroll
        for (int ni = 0; ni < 2; ++ni) acc[mi][ni] = {0.f, 0.f, 0.f, 0.f};

    float4 fa[2][2];

    auto a_load = [&](int k0) {
        #pragma unroll
        for (int p = 0; p < 2; ++p) {
            int row = p * 64 + tr;
            int grow = m0 + row; if (grow > M - 1) grow = M - 1;
            const float* s = (const float*)Av + (size_t)grow * KDIM + k0 + tk * 8;
            fa[p][0] = *reinterpret_cast<const float4*>(s);
            fa[p][1] = *reinterpret_cast<const float4*>(s + 4);
        }
    };
    auto a_write = [&](int buf) {
        #pragma unroll
        for (int p = 0; p < 2; ++p) {
            int row = p * 64 + tr;
            short8 sh;
            sh[0] = (short)f2bf_u(fa[p][0].x); sh[1] = (short)f2bf_u(fa[p][0].y);
            sh[2] = (short)f2bf_u(fa[p][0].z); sh[3] = (short)f2bf_u(fa[p][0].w);
            sh[4] = (short)f2bf_u(fa[p][1].x); sh[5] = (short)f2bf_u(fa[p][1].y);
            sh[6] = (short)f2bf_u(fa[p][1].z); sh[7] = (short)f2bf_u(fa[p][1].w);
            *reinterpret_cast<short8*>(&sAp[buf * 8192 + row * 64 + ((tk ^ (row & 7)) << 3)]) = sh;
        }
    };
    auto a_dma = [&](int buf, int k0) {
        #pragma unroll
        for (int p = 0; p < 2; ++p) {
            int row = p * 64 + wave * 8 + l8r;
            int grow = m0 + row; if (grow > M - 1) grow = M - 1;
            const short* s = (const short*)Av + (size_t)grow * KDIM + k0 + ((l8u ^ (row & 7)) << 3);
            GLOAD_LDS16(s, sAp + buf * 8192 + p * 4096 + wave * 512);
        }
    };
    auto b_dma = [&](int buf, int k0) {
        int row = wave * 8 + l8r;
        size_t goff = (size_t)(n0 + row) * KDIM + k0 + ((l8u ^ (row & 7)) << 3);
        GLOAD_LDS16(Bh + goff, sBp + (buf * 2 + 0) * 4096 + wave * 512);
        GLOAD_LDS16(Bl + goff, sBp + (buf * 2 + 1) * 4096 + wave * 512);
    };

    if (AF32) {
        a_load(0);
        b_dma(0, 0);
        asm volatile("s_waitcnt vmcnt(0)" ::: "memory");
        a_write(0);
        __syncthreads();
    } else {
        a_dma(0, 0);
        b_dma(0, 0);
        asm volatile("s_waitcnt vmcnt(0)" ::: "memory");
        __builtin_amdgcn_s_barrier();
        asm volatile("" ::: "memory");
    }

    int cur = 0;
    #pragma unroll 1
    for (int t = 0; t < NT; ++t) {
        const bool pf = (t + 1 < NT);
        if (pf) {
            if (AF32) a_load((t + 1) * 64);
            else      a_dma(cur ^ 1, (t + 1) * 64);
            b_dma(cur ^ 1, (t + 1) * 64);
        }
        #pragma unroll
        for (int ks = 0; ks < 2; ++ks) {
            int kg = ks * 4 + lk;
            bf16x8 af[2], bhf[2], blf[2];
            #pragma unroll
            for (int mi = 0; mi < 2; ++mi) {
                int row = wr * 32 + mi * 16 + lr;
                af[mi] = *reinterpret_cast<const bf16x8*>(
                    &sAp[cur * 8192 + row * 64 + ((kg ^ (row & 7)) << 3)]);
            }
            #pragma unroll
            for (int ni = 0; ni < 2; ++ni) {
                int row = wc * 32 + ni * 16 + lr;
                int idx = row * 64 + ((kg ^ (row & 7)) << 3);
                bhf[ni] = *reinterpret_cast<const bf16x8*>(&sBp[(cur * 2 + 0) * 4096 + idx]);
                blf[ni] = *reinterpret_cast<const bf16x8*>(&sBp[(cur * 2 + 1) * 4096 + idx]);
            }
            #pragma unroll
            for (int mi = 0; mi < 2; ++mi)
                #pragma unroll
                for (int ni = 0; ni < 2; ++ni) {
                    acc[mi][ni] = __builtin_amdgcn_mfma_f32_16x16x32_bf16(af[mi], bhf[ni], acc[mi][ni], 0, 0, 0);
                    acc[mi][ni] = __builtin_amdgcn_mfma_f32_16x16x32_bf16(af[mi], blf[ni], acc[mi][ni], 0, 0, 0);
                }
        }
        asm volatile("s_waitcnt vmcnt(0)" ::: "memory");
        if (AF32) { if (pf) a_write(cur ^ 1); __syncthreads(); }
        else { __builtin_amdgcn_s_barrier(); asm volatile("" ::: "memory"); }
        cur ^= 1;
    }

    #pragma unroll
    for (int ni = 0; ni < 2; ++ni) {
        int col = n0 + wc * 32 + ni * 16 + lr;
        float bv = bias[col];
        #pragma unroll
        for (int mi = 0; mi < 2; ++mi) {
            #pragma unroll
            for (int r = 0; r < 4; ++r) {
                int row = m0 + wr * 32 + mi * 16 + lk * 4 + r;
                if (row < M) {
                    float v = acc[mi][ni][r] + bv;
                    if (RELU) v = fmaxf(v, 0.0f);
                    C[(size_t)row * LDC + col] = (short)f2bf_u(v);
                }
            }
        }
    }
}

__global__ __launch_bounds__(512)
void gemm1_k(const float* __restrict__ x, const short* __restrict__ W1h,
             const short* __restrict__ W1l, const float* __restrict__ b1,
             short* __restrict__ Hbf, int M) {
    __shared__ short sAp[2 * 128 * 64];
    __shared__ short sBp[2 * 2 * 64 * 64];
    int t = blockIdx.x;
    gemm_tile<512, 256, true, true>(x, W1h, W1l, b1, Hbf, M, (t >> 2) * 128, (t & 3) * 64, sAp, sBp);
}

__global__ __launch_bounds__(512)
void gemm2_k(const short* __restrict__ Hbf, const short* __restrict__ W2h,
             const short* __restrict__ W2l, const float* __restrict__ b2,
             short* __restrict__ zbf, int M) {
    __shared__ short sAp[2 * 128 * 64];
    __shared__ short sBp[2 * 2 * 64 * 64];
    gemm_tile<256, 64, false, false>(Hbf, W2h, W2l, b2, zbf, M, blockIdx.x * 128, 0, sAp, sBp);
}

// ==================================================================
// Propagation step: one wave per node, lane = channel.
// 8-wide batches with NEXT-batch csr prefetch (uniform-load latency off
// the critical path). Edge order ascending -> bit-identical to r9.
// ==================================================================
__global__ __launch_bounds__(256)
void prop_step(const unsigned short* __restrict__ hin, const unsigned short* __restrict__ zbf,
               const int* __restrict__ rowptr, const int2* __restrict__ csr,
               const float* __restrict__ dinv, void* __restrict__ hout,
               int outf32, int n) {
    int node = blockIdx.x * 4 + (threadIdx.x >> 6);
    int lane = threadIdx.x & 63;
    if (node >= n) return;
    float di = dinv[node];
    int base = node << 6;
    float acc = bf2f(hin[base + lane]) * (di * di);
    int e = rowptr[node], e1 = rowptr[node + 1];

    if (e + 8 <= e1) {
        int2 r[8];
        #pragma unroll
        for (int j = 0; j < 8; ++j) r[j] = csr[e + j];
        for (; e + 16 <= e1; e += 8) {
            int2 rn[8];
            #pragma unroll
            for (int j = 0; j < 8; ++j) rn[j] = csr[e + 8 + j];
            unsigned short v[8];
            #pragma unroll
            for (int j = 0; j < 8; ++j) v[j] = hin[((unsigned)r[j].x << 6) + lane];
            #pragma unroll
            for (int j = 0; j < 8; ++j) acc = fmaf(bf2f(v[j]), i2f(r[j].y), acc);
            #pragma unroll
            for (int j = 0; j < 8; ++j) r[j] = rn[j];
        }
        {   // drain last full batch
            unsigned short v[8];
            #pragma unroll
            for (int j = 0; j < 8; ++j) v[j] = hin[((unsigned)r[j].x << 6) + lane];
            #pragma unroll
            for (int j = 0; j < 8; ++j) acc = fmaf(bf2f(v[j]), i2f(r[j].y), acc);
            e += 8;
        }
    }
    for (; e + 4 <= e1; e += 4) {
        int2 r[4]; unsigned short v[4];
        #pragma unroll
        for (int j = 0; j < 4; ++j) r[j] = csr[e + j];
        #pragma unroll
        for (int j = 0; j < 4; ++j) v[j] = hin[((unsigned)r[j].x << 6) + lane];
        #pragma unroll
        for (int j = 0; j < 4; ++j) acc = fmaf(bf2f(v[j]), i2f(r[j].y), acc);
    }
    for (; e < e1; ++e) {
        int2 r = csr[e];
        acc = fmaf(bf2f(hin[((unsigned)r.x << 6) + lane]), i2f(r.y), acc);
    }

    float res = 0.9f * acc + 0.1f * bf2f(zbf[base + lane]);
    if (outf32) ((float*)hout)[base + lane] = res;
    else        ((unsigned short*)hout)[base + lane] = f2bf_u(res);
}

// ==================================================================
extern "C" void kernel_launch(void* const* d_in, const int* in_sizes, int n_in,
                              void* d_out, int out_size, void* d_ws, size_t ws_size,
                              hipStream_t stream) {
    const float* x  = (const float*)d_in[0];
    const void*  ei = d_in[1];
    const float* W1 = (const float*)d_in[2];
    const float* b1 = (const float*)d_in[3];
    const float* W2 = (const float*)d_in[4];
    const float* b2 = (const float*)d_in[5];
    float* dout = (float*)d_out;

    const int IN_C = 512, HID_C = 256, OUT_C = 64, Ksteps = 10;
    const int N = in_sizes[0] / IN_C;   // 50000
    const int E = in_sizes[1] / 2;      // 800000

    char* w = (char*)d_ws;
    auto alloc = [&](size_t bytes) { char* p = w; w += (bytes + 255) & ~(size_t)255; return p; };
    int*   flag    = (int*)  alloc(4);
    int*   src32   = (int*)  alloc((size_t)E * 4);
    int*   dst32   = (int*)  alloc((size_t)E * 4);
    int*   counts  = (int*)  alloc((size_t)N * 4);
    int*   rowptr  = (int*)  alloc((size_t)(N + 1) * 4);
    int*   cursor  = (int*)  alloc((size_t)N * 4);
    float* dinv    = (float*)alloc((size_t)N * 4);
    int2*  csr     = (int2*) alloc((size_t)E * 8);
    short* W1h     = (short*)alloc((size_t)HID_C * IN_C * 2);
    short* W1l     = (short*)alloc((size_t)HID_C * IN_C * 2);
    short* W2h     = (short*)alloc((size_t)OUT_C * HID_C * 2);
    short* W2l     = (short*)alloc((size_t)OUT_C * HID_C * 2);
    short* Hbf     = (short*)alloc((size_t)N * HID_C * 2);
    unsigned short* zbf = (unsigned short*)alloc((size_t)N * OUT_C * 2);
    unsigned short* hA  = (unsigned short*)alloc((size_t)N * OUT_C * 2);
    unsigned short* hB  = (unsigned short*)alloc((size_t)N * OUT_C * 2);
    int*   bs      = (int*)  alloc(256 * 4);
    int*   bsoff   = (int*)  alloc(256 * 4);

    hipMemsetAsync(flag, 0, 4, stream);
    hipMemsetAsync(counts, 0, (size_t)N * 4, stream);

    const int egrid = (E + 255) / 256;
    const int nblk = (N + 255) / 256;
    const int mgrid = (N + 127) / 128;
    const int pgrid = (N + 3) / 4;

    // preprocessing (6 dispatches)
    prep_a<<<512, 256, 0, stream>>>(ei, W1, W2, flag, W1h, W1l, W2h, W2l);
    convert_count_kernel<<<egrid, 256, 0, stream>>>(ei, flag, src32, dst32, counts, E);
    bsum_dinv_kernel<<<nblk, 256, 0, stream>>>(counts, dinv, bs, N);
    scanbs_kernel<<<1, 256, 0, stream>>>(bs, bsoff, nblk);
    scanblock_kernel<<<nblk, 256, 0, stream>>>(counts, bsoff, rowptr, cursor, N);
    fill_kernel<<<egrid, 256, 0, stream>>>(src32, dst32, dinv, cursor, csr, E);

    // GEMM1: full-width 160 KB-LDS kernel if the device allows it; else r10 path
    constexpr int G1_LDS = 163840;
    bool big = hipFuncSetAttribute((const void*)gemm1f_k,
                                   hipFuncAttributeMaxDynamicSharedMemorySize,
                                   G1_LDS) == hipSuccess;
    if (big) {
        gemm1f_k<<<mgrid, 512, G1_LDS, stream>>>(x, W1h, W1l, b1, Hbf, N);
        if (hipGetLastError() != hipSuccess) big = false;
    }
    if (!big) {
        gemm1_k<<<mgrid * 4, 512, 0, stream>>>(x, W1h, W1l, b1, Hbf, N);
    }
    gemm2_k<<<mgrid, 512, 0, stream>>>(Hbf, W2h, W2l, b2, (short*)zbf, N);

    // propagation: h^(0)=z in zbf; ping-pong hA/hB; last step writes fp32 dout
    const unsigned short* pin = zbf;
    for (int s = 0; s < Ksteps; ++s) {
        bool last = (s == Ksteps - 1);
        void* out = last ? (void*)dout : ((s & 1) ? (void*)hB : (void*)hA);
        prop_step<<<pgrid, 256, 0, stream>>>(pin, zbf, rowptr, csr, dinv,
                                             out, last ? 1 : 0, N);
        pin = (const unsigned short*)out;
    }
}